// Round 7
// baseline (199.122 us; speedup 1.0000x reference)
//
#include <hip/hip_runtime.h>

// FBPinn 1D, NW=16 windows, MLP 1->64->64->64->1 (tanh), sigmoid windows.
//   pass1: bucket point indices per window (LDS histogram + 16 global
//          atomics/block); zeroes out[].
//   pass2: one window per block-column. Accumulators = 4x float16 SSA
//          ext-vectors (VGPR-pinned). h staged in LDS as _Float16 (32KB ->
//          >=3 blocks/CU). Weight rows read via per-lane VECTOR global loads
//          (vmcnt: in-order, prefetchable, L1-broadcast) -- NOT s_load.
//   [R2: dynamic h[ii] -> scratch 94MB]
//   [R3: full unroll -> >32KB I$, 186us]
//   [R4/R5: C-array acc + rolled loop -> alloca scratch 120MB]
//   [R6: s_load weights: SMEM is out-of-order -> lgkmcnt(0) drain per ii,
//        unpipelinable; 64KB LDS -> 2 waves/SIMD; VALUBusy 31%, 62us]
// Workspace: int cnt[16*16] (64B stride/window) @0, int list[16*CAP] @1024.

#define NW    16
#define NEUR  64
#define BLK   256
#define CAP   10240
#define CSTR  16

typedef float v16f __attribute__((ext_vector_type(16)));

__device__ __forceinline__ float fast_tanh(float x) {
    float e = __expf(x + x);
    return 1.0f - 2.0f * __builtin_amdgcn_rcpf(e + 1.0f);
}
__device__ __forceinline__ float fast_sigmoid(float z) {
    return __builtin_amdgcn_rcpf(1.0f + __expf(-z));
}

__global__ __launch_bounds__(1024) void pass1_bucket(
    const float* __restrict__ x, int n,
    int* __restrict__ cnt, int* __restrict__ list,
    float* __restrict__ out) {
    __shared__ int lcnt[NW];
    __shared__ int lbase[NW];
    const int tid = threadIdx.x;
    if (tid < NW) lcnt[tid] = 0;
    __syncthreads();

    const int i = blockIdx.x * 1024 + tid;
    int w0 = -1, w1 = -1, p0 = 0, p1 = 0;
    if (i < n) {
        out[i] = 0.0f;
        float xv = x[i];
        #pragma unroll
        for (int w = 0; w < NW; ++w) {
            float lo = (w == 0)      ? 0.0f   : ((float)w - 0.125f) * 6.25f;
            float hi = (w == NW - 1) ? 100.0f : ((float)w + 1.125f) * 6.25f;
            if (lo < xv && xv < hi) {         // exact strict compares
                if (w0 < 0) w0 = w; else w1 = w;
            }
        }
        if (w0 >= 0) p0 = atomicAdd(&lcnt[w0], 1);
        if (w1 >= 0) p1 = atomicAdd(&lcnt[w1], 1);
    }
    __syncthreads();
    if (tid < NW)
        lbase[tid] = atomicAdd(&cnt[tid * CSTR], lcnt[tid]);
    __syncthreads();

    if (w0 >= 0) { int p = lbase[w0] + p0; if (p < CAP) list[w0 * CAP + p] = i; }
    if (w1 >= 0) { int p = lbase[w1] + p1; if (p < CAP) list[w1 * CAP + p] = i; }
}

__global__ __launch_bounds__(256, 3) void pass2_mlp(
    const float* __restrict__ x,
    const float* __restrict__ W_in, const float* __restrict__ b_in,
    const float* __restrict__ W_h,  const float* __restrict__ b_h,
    const float* __restrict__ W_out, const float* __restrict__ b_out,
    const int* __restrict__ cnt, const int* __restrict__ list,
    float* __restrict__ out) {
    __shared__ _Float16 hbuf[NEUR * BLK];         // 32 KB, column per thread
    const int tid = threadIdx.x;
    const int w   = blockIdx.y;
    const int count = min(cnt[w * CSTR], CAP);

    // Opaque zero in a VGPR: forces weight addresses to be vector (vmcnt
    // global_load path), not scalarized to out-of-order SMEM s_load.
    int zoff;
    asm volatile("v_mov_b32 %0, 0" : "=v"(zoff));

    float lo = (w == 0)      ? 0.0f   : ((float)w - 0.125f) * 6.25f;
    float hi = (w == NW - 1) ? 100.0f : ((float)w + 1.125f) * 6.25f;
    float mean    = 0.5f * (lo + hi);
    float inv_std = 1.0f / (0.5f * (hi - lo));
    float ow0 = (float)w * 6.25f;
    float ow1 = (float)(w + 1) * 6.25f;

    const float* Wi = W_in  + w * NEUR;
    const float* bi = b_in  + w * NEUR;
    const float* b0 = b_h   + (0 * NW + w) * NEUR;
    const float* b1 = b_h   + (1 * NW + w) * NEUR;
    const float* Wo = W_out + w * NEUR;
    const float bo  = b_out[w];
    const char* W0p = (const char*)(W_h + (0 * NW + w) * NEUR * NEUR) + zoff;
    const char* W1p = (const char*)(W_h + (1 * NW + w) * NEUR * NEUR) + zoff;

    for (int base = blockIdx.x * BLK; base < count; base += BLK * gridDim.x) {
        int  k      = base + tid;
        bool active = (k < count);
        int  kk     = active ? k : 0;
        int  i      = list[w * CAP + kk];
        float xv = x[i];
        float xn = (xv - mean) * inv_std;

        // input layer -> LDS column (fp16)
        #pragma unroll 8
        for (int o = 0; o < NEUR; ++o)
            hbuf[o * BLK + tid] = (_Float16)fast_tanh(fmaf(xn, Wi[o], bi[o]));

        // ---- hidden layer 1 ----
        v16f A0, A1, A2, A3;
        #pragma unroll
        for (int o = 0; o < 16; ++o) {
            A0[o] = b0[o];      A1[o] = b0[16 + o];
            A2[o] = b0[32 + o]; A3[o] = b0[48 + o];
        }
        #pragma unroll 1
        for (int ii = 0; ii < NEUR; ++ii) {
            float hv = (float)hbuf[ii * BLK + tid];
            const v16f* rp = (const v16f*)(W0p + (ii << 8));
            v16f wA = rp[0], wB = rp[1], wC = rp[2], wD = rp[3];
            #pragma unroll
            for (int o = 0; o < 16; ++o) {
                A0[o] = fmaf(hv, wA[o], A0[o]);
                A1[o] = fmaf(hv, wB[o], A1[o]);
                A2[o] = fmaf(hv, wC[o], A2[o]);
                A3[o] = fmaf(hv, wD[o], A3[o]);
            }
        }
        #pragma unroll 4
        for (int o = 0; o < 16; ++o) {
            hbuf[o * BLK + tid]        = (_Float16)fast_tanh(A0[o]);
            hbuf[(16 + o) * BLK + tid] = (_Float16)fast_tanh(A1[o]);
            hbuf[(32 + o) * BLK + tid] = (_Float16)fast_tanh(A2[o]);
            hbuf[(48 + o) * BLK + tid] = (_Float16)fast_tanh(A3[o]);
        }

        // ---- hidden layer 2 ----
        #pragma unroll
        for (int o = 0; o < 16; ++o) {
            A0[o] = b1[o];      A1[o] = b1[16 + o];
            A2[o] = b1[32 + o]; A3[o] = b1[48 + o];
        }
        #pragma unroll 1
        for (int ii = 0; ii < NEUR; ++ii) {
            float hv = (float)hbuf[ii * BLK + tid];
            const v16f* rp = (const v16f*)(W1p + (ii << 8));
            v16f wA = rp[0], wB = rp[1], wC = rp[2], wD = rp[3];
            #pragma unroll
            for (int o = 0; o < 16; ++o) {
                A0[o] = fmaf(hv, wA[o], A0[o]);
                A1[o] = fmaf(hv, wB[o], A1[o]);
                A2[o] = fmaf(hv, wC[o], A2[o]);
                A3[o] = fmaf(hv, wD[o], A3[o]);
            }
        }
        #pragma unroll 4
        for (int o = 0; o < 16; ++o) {
            hbuf[o * BLK + tid]        = (_Float16)fast_tanh(A0[o]);
            hbuf[(16 + o) * BLK + tid] = (_Float16)fast_tanh(A1[o]);
            hbuf[(32 + o) * BLK + tid] = (_Float16)fast_tanh(A2[o]);
            hbuf[(48 + o) * BLK + tid] = (_Float16)fast_tanh(A3[o]);
        }

        // output layer
        float outv = bo;
        #pragma unroll 8
        for (int o = 0; o < NEUR; ++o)
            outv = fmaf((float)hbuf[o * BLK + tid], Wo[o], outv);

        float win = fast_sigmoid((xv - ow0) * 2.0f) *
                    fast_sigmoid((ow1 - xv) * 2.0f);

        if (active) atomicAdd(&out[i], win * outv);
    }
}

extern "C" void kernel_launch(void* const* d_in, const int* in_sizes, int n_in,
                              void* d_out, int out_size, void* d_ws, size_t ws_size,
                              hipStream_t stream) {
    const float* x     = (const float*)d_in[0];
    const float* W_in  = (const float*)d_in[1];
    const float* b_in  = (const float*)d_in[2];
    const float* W_h   = (const float*)d_in[3];
    const float* b_h   = (const float*)d_in[4];
    const float* W_out = (const float*)d_in[5];
    const float* b_out = (const float*)d_in[6];
    float* out = (float*)d_out;
    const int n = in_sizes[0];

    int* cnt  = (int*)d_ws;
    int* list = (int*)((char*)d_ws + 1024);

    hipMemsetAsync(cnt, 0, NW * CSTR * sizeof(int), stream);

    pass1_bucket<<<(n + 1023) / 1024, 1024, 0, stream>>>(x, n, cnt, list, out);

    dim3 grid(32, NW);
    pass2_mlp<<<grid, BLK, 0, stream>>>(x, W_in, b_in, W_h, b_h, W_out, b_out,
                                        cnt, list, out);
}

// Round 10
// 84.617 us; speedup vs baseline: 2.3532x; 2.3532x over previous
//
#include <hip/hip_runtime.h>

// FBPinn 1D, NW=16 windows, MLP 1->64->64->64->1 (tanh), sigmoid windows.
// pass2 = MFMA v_mfma_f32_16x16x32_f16. All lane mappings HW-verified
// (m89/m91/m120/m122); moreover the packing is invariant to the common A/B
// k-mapping (both sides packed with the same assumed bijection).
//   C/D: col=lane&15, row=(lane>>4)*4+reg
//   A/B: m|n=lane&15, k=(lane>>4)*8+j
// [R8: absmax 1.1 — biasH OOB write + missing LDS fences]
// [R9: absmax 0.34 — ROOT CAUSE: cross-lane LDS comm (Hp) with NO sync.
//  Compiler may hoist a lane's ds_read above other-lane-producing ds_writes
//  when disjoint from ITS OWN writes (warp-sync UB). FIX: compiler memory
//  fences at every DS phase transition; HW same-wave DS order does the rest.]
// pass1: LDS-histogram bucketing (known-good since R2).

#define NW    16
#define NEUR  64
#define BLK   256
#define CAP   10240
#define CSTR  16
#define GX    128      // grid.x: 128 blocks x 64 pts = 8192 slots/window
#define DSFENCE() asm volatile("" ::: "memory")

typedef _Float16 v8h __attribute__((ext_vector_type(8)));
typedef float    v4f __attribute__((ext_vector_type(4)));
typedef _Float16 h2  __attribute__((ext_vector_type(2)));
typedef unsigned v4u __attribute__((ext_vector_type(4)));

__device__ __forceinline__ float fast_tanh(float x) {
    float e = __expf(x + x);
    return 1.0f - 2.0f * __builtin_amdgcn_rcpf(e + 1.0f);
}
__device__ __forceinline__ float fast_sigmoid(float z) {
    return __builtin_amdgcn_rcpf(1.0f + __expf(-z));
}
__device__ __forceinline__ v8h zero8() {
    v8h z;
    #pragma unroll
    for (int j = 0; j < 8; ++j) z[j] = (_Float16)0.0f;
    return z;
}

__global__ __launch_bounds__(1024) void pass1_bucket(
    const float* __restrict__ x, int n,
    int* __restrict__ cnt, int* __restrict__ list,
    float* __restrict__ out) {
    __shared__ int lcnt[NW];
    __shared__ int lbase[NW];
    const int tid = threadIdx.x;
    if (tid < NW) lcnt[tid] = 0;
    __syncthreads();

    const int i = blockIdx.x * 1024 + tid;
    int w0 = -1, w1 = -1, p0 = 0, p1 = 0;
    if (i < n) {
        out[i] = 0.0f;
        float xv = x[i];
        #pragma unroll
        for (int w = 0; w < NW; ++w) {
            float lo = (w == 0)      ? 0.0f   : ((float)w - 0.125f) * 6.25f;
            float hi = (w == NW - 1) ? 100.0f : ((float)w + 1.125f) * 6.25f;
            if (lo < xv && xv < hi) {           // exact strict compares
                if (w0 < 0) w0 = w; else w1 = w;
            }
        }
        if (w0 >= 0) p0 = atomicAdd(&lcnt[w0], 1);
        if (w1 >= 0) p1 = atomicAdd(&lcnt[w1], 1);
    }
    __syncthreads();
    if (tid < NW)
        lbase[tid] = atomicAdd(&cnt[tid * CSTR], lcnt[tid]);
    __syncthreads();

    if (w0 >= 0) { int p = lbase[w0] + p0; if (p < CAP) list[w0 * CAP + p] = i; }
    if (w1 >= 0) { int p = lbase[w1] + p1; if (p < CAP) list[w1 * CAP + p] = i; }
}

__global__ __launch_bounds__(256) void pass2_mlp(
    const float* __restrict__ x,
    const float* __restrict__ W_in, const float* __restrict__ b_in,
    const float* __restrict__ W_h,  const float* __restrict__ b_h,
    const float* __restrict__ W_out, const float* __restrict__ b_out,
    const int* __restrict__ cnt, const int* __restrict__ list,
    float* __restrict__ out, int npts) {
    __shared__ _Float16 aH[16 * 512];     // [l*8+mt*2+ks] frags, 16 KB
    __shared__ _Float16 aIn[4 * 512];     // [mt] frags,           4 KB
    __shared__ _Float16 aOut[2 * 512];    // [ks] frags,           2 KB
    __shared__ float    biasH[128];       // hidden biases fp32
    __shared__ unsigned Hp[4 * 512];      // [wid][k2 0..31][n 0..15], 8 KB

    const int tid = threadIdx.x;
    const int w   = blockIdx.y;
    const int count = min(cnt[w * CSTR], GX * 64);
    if (blockIdx.x * 64 >= count) return;          // uniform: whole block

    const int lane = tid & 63;
    const int wid  = tid >> 6;
    const int n16  = lane & 15;
    const int quad = lane >> 4;

    // ---- prepack A-fragments (once per block) ----
    #pragma unroll
    for (int p = 0; p < 4; ++p) {                  // hidden: 16 frags
        int f  = wid * 4 + p;                      // f = l*8 + mt*2 + ks
        int l  = f >> 3, mt = (f >> 1) & 3, ks = f & 1;
        const float* Ws = W_h + (l * NW + w) * 4096;
        int m  = mt * 16 + n16;
        int k0 = ks * 32 + quad * 8;
        v8h a;
        #pragma unroll
        for (int j = 0; j < 8; ++j)
            a[j] = (_Float16)Ws[(k0 + j) * 64 + m];   // A[m][k]=W[k][m]
        *(v8h*)(&aH[f * 512 + lane * 8]) = a;
    }
    {   // input frags: A[m][0]=Wi[m], A[m][1]=bi[m]
        int mt = wid, m = mt * 16 + n16;
        v8h a = zero8();
        if (quad == 0) {
            a[0] = (_Float16)W_in[w * 64 + m];
            a[1] = (_Float16)b_in[w * 64 + m];
        }
        *(v8h*)(&aIn[mt * 512 + lane * 8]) = a;
    }
    if (wid < 2) {  // output frags: A[0][k]=Wo[k], rows m>0 zero
        int ks = wid;
        v8h a = zero8();
        if (n16 == 0) {
            int k0 = ks * 32 + quad * 8;
            #pragma unroll
            for (int j = 0; j < 8; ++j)
                a[j] = (_Float16)W_out[w * 64 + k0 + j];
        }
        *(v8h*)(&aOut[ks * 512 + lane * 8]) = a;
    }
    if (tid < 128)
        biasH[tid] = b_h[((tid >> 6) * NW + w) * 64 + (tid & 63)];
    __syncthreads();

    // ---- per-wave: 16 points ----
    float lo = (w == 0)      ? 0.0f   : ((float)w - 0.125f) * 6.25f;
    float hi = (w == NW - 1) ? 100.0f : ((float)w + 1.125f) * 6.25f;
    float mean    = 0.5f * (lo + hi);
    float inv_std = 1.0f / (0.5f * (hi - lo));
    float ow0 = (float)w * 6.25f;
    float ow1 = (float)(w + 1) * 6.25f;
    float bo  = b_out[w];

    int  kpt = blockIdx.x * 64 + wid * 16 + n16;
    bool act = (kpt < count) && (lane < 16);
    int  kk  = (kpt < count) ? kpt : 0;
    int  idx = list[w * CAP + kk];
    if ((unsigned)idx >= (unsigned)npts) idx = 0;  // poison guard
    float xv = x[idx];
    float xn = (xv - mean) * inv_std;

    unsigned* HpW = Hp + wid * 512;

    // input layer: pre = Wi*xn + bi, tanh -> Hp
    {
        v8h b = zero8();
        if (quad == 0) { b[0] = (_Float16)xn; b[1] = (_Float16)1.0f; }
        #pragma unroll
        for (int mt = 0; mt < 4; ++mt) {
            v4f c = {0.0f, 0.0f, 0.0f, 0.0f};
            v8h a = *(const v8h*)(&aIn[mt * 512 + lane * 8]);
            c = __builtin_amdgcn_mfma_f32_16x16x32_f16(a, b, c, 0, 0, 0);
            int k2 = mt * 8 + quad * 2;            // pair rows, m0 even
            h2 q0, q1;
            q0[0] = (_Float16)fast_tanh(c[0]);
            q0[1] = (_Float16)fast_tanh(c[1]);
            q1[0] = (_Float16)fast_tanh(c[2]);
            q1[1] = (_Float16)fast_tanh(c[3]);
            HpW[k2 * 16 + n16]       = __builtin_bit_cast(unsigned, q0);
            HpW[(k2 + 1) * 16 + n16] = __builtin_bit_cast(unsigned, q1);
        }
    }
    DSFENCE();   // writes(input) -> reads(hidden0): cross-lane handoff

    // hidden layers: D = W^T*H (+bias), tanh, back to Hp
    #pragma unroll
    for (int l = 0; l < 2; ++l) {
        v4f d0 = {0.0f,0.0f,0.0f,0.0f}, d1 = d0, d2 = d0, d3 = d0;
        #pragma unroll
        for (int ks = 0; ks < 2; ++ks) {
            v4u bw;
            #pragma unroll
            for (int j2 = 0; j2 < 4; ++j2)
                bw[j2] = HpW[(ks * 16 + quad * 4 + j2) * 16 + n16];
            v8h b = __builtin_bit_cast(v8h, bw);
            d0 = __builtin_amdgcn_mfma_f32_16x16x32_f16(
                     *(const v8h*)(&aH[(l*8 + 0*2 + ks)*512 + lane*8]), b, d0, 0,0,0);
            d1 = __builtin_amdgcn_mfma_f32_16x16x32_f16(
                     *(const v8h*)(&aH[(l*8 + 1*2 + ks)*512 + lane*8]), b, d1, 0,0,0);
            d2 = __builtin_amdgcn_mfma_f32_16x16x32_f16(
                     *(const v8h*)(&aH[(l*8 + 2*2 + ks)*512 + lane*8]), b, d2, 0,0,0);
            d3 = __builtin_amdgcn_mfma_f32_16x16x32_f16(
                     *(const v8h*)(&aH[(l*8 + 3*2 + ks)*512 + lane*8]), b, d3, 0,0,0);
        }
        DSFENCE();   // reads(layer l) -> writes(layer l)
        const float* bl = biasH + l * 64;
        #pragma unroll
        for (int mt = 0; mt < 4; ++mt) {
            v4f d = (mt == 0) ? d0 : (mt == 1) ? d1 : (mt == 2) ? d2 : d3;
            int m0 = mt * 16 + quad * 4;           // even
            int k2 = m0 >> 1;
            h2 q0, q1;
            q0[0] = (_Float16)fast_tanh(d[0] + bl[m0]);
            q0[1] = (_Float16)fast_tanh(d[1] + bl[m0 + 1]);
            q1[0] = (_Float16)fast_tanh(d[2] + bl[m0 + 2]);
            q1[1] = (_Float16)fast_tanh(d[3] + bl[m0 + 3]);
            HpW[k2 * 16 + n16]       = __builtin_bit_cast(unsigned, q0);
            HpW[(k2 + 1) * 16 + n16] = __builtin_bit_cast(unsigned, q1);
        }
        DSFENCE();   // writes(layer l) -> reads(next phase)
    }

    // output layer: A row0 = Wo -> e[0] on lanes 0..15 is out[n]
    {
        v4f e = {0.0f, 0.0f, 0.0f, 0.0f};
        #pragma unroll
        for (int ks = 0; ks < 2; ++ks) {
            v4u bw;
            #pragma unroll
            for (int j2 = 0; j2 < 4; ++j2)
                bw[j2] = HpW[(ks * 16 + quad * 4 + j2) * 16 + n16];
            v8h b = __builtin_bit_cast(v8h, bw);
            e = __builtin_amdgcn_mfma_f32_16x16x32_f16(
                    *(const v8h*)(&aOut[ks * 512 + lane * 8]), b, e, 0, 0, 0);
        }
        float outv = e[0] + bo;
        float win = fast_sigmoid((xv - ow0) * 2.0f) *
                    fast_sigmoid((ow1 - xv) * 2.0f);
        if (act) atomicAdd(&out[idx], win * outv);
    }
}

extern "C" void kernel_launch(void* const* d_in, const int* in_sizes, int n_in,
                              void* d_out, int out_size, void* d_ws, size_t ws_size,
                              hipStream_t stream) {
    const float* x     = (const float*)d_in[0];
    const float* W_in  = (const float*)d_in[1];
    const float* b_in  = (const float*)d_in[2];
    const float* W_h   = (const float*)d_in[3];
    const float* b_h   = (const float*)d_in[4];
    const float* W_out = (const float*)d_in[5];
    const float* b_out = (const float*)d_in[6];
    float* out = (float*)d_out;
    const int n = in_sizes[0];

    int* cnt  = (int*)d_ws;
    int* list = (int*)((char*)d_ws + 1024);

    hipMemsetAsync(cnt, 0, NW * CSTR * sizeof(int), stream);

    pass1_bucket<<<(n + 1023) / 1024, 1024, 0, stream>>>(x, n, cnt, list, out);

    dim3 grid(GX, NW);
    pass2_mlp<<<grid, BLK, 0, stream>>>(x, W_in, b_in, W_h, b_h, W_out, b_out,
                                        cnt, list, out, n);
}